// Round 4
// baseline (178.931 us; speedup 1.0000x reference)
//
#include <hip/hip_runtime.h>

// Problem constants (fixed by setup_inputs).
#define B_    16
#define C_    3
#define H_    512
#define W_    1024
#define MW    256          // mask_width
#define RS    16           // output rows per wave-strip
#define NRS   32           // 32*16 = 512 exact (no ragged strip)
#define NIN   (RS + 10)    // 26 input rows streamed per strip

#define FENCE() do { __builtin_amdgcn_sched_barrier(0); \
                     __builtin_amdgcn_wave_barrier();   \
                     __builtin_amdgcn_sched_barrier(0); } while (0)

__global__ __launch_bounds__(256) void ssim_main(const float* __restrict__ img1,
                                                 const float* __restrict__ img2,
                                                 const int*   __restrict__ mask_pos,
                                                 float*       __restrict__ accum) {
    // Gaussian weights = float64 exp/normalize, precomputed to float literals.
    constexpr float G[11] = {
        0.00102838f, 0.00759876f, 0.03600077f, 0.10936070f, 0.21300553f,
        0.26601173f, 0.21300553f, 0.10936070f, 0.03600077f, 0.00759876f,
        0.00102838f };

    // Per-wave DOUBLE-BUFFERED 74-col {img1,img2} row ring. 5 KB total.
    __shared__ float2 rowbuf[4][2][80];
    __shared__ float  blksum[4];

    const int tid  = threadIdx.x;
    const int w    = tid >> 6;
    const int lane = tid & 63;

    const int blk   = blockIdx.x;
    const int strip = blk & (NRS - 1);   // row strip 0..31
    const int bc    = blk >> 5;          // (b,ch) 0..47
    const int b     = bc / 3;

    int s0 = mask_pos[b];
    s0 = min(max(s0, 0), W_ - MW);

    const float* __restrict__ p1 = img1 + (size_t)bc * (H_ * W_);
    const float* __restrict__ p2 = img2 + (size_t)bc * (H_ * W_);

    const int y0  = strip * RS;
    const int sx0 = w << 6;              // column strip base within crop
    const int cxm = sx0 - 5 + lane;      // main staged column (crop coords)
    const int cxh = sx0 + 59 + lane;     // halo staged column (lane < 10)
    const bool vm = (cxm >= 0) && (cxm < MW);
    const bool vh = (lane < 10) && (cxh < MW);
    const int gxm = s0 + cxm;
    const int gxh = s0 + cxh;

    // Prefetch register sets, indexed by row parity (all indices compile-time).
    float pre[2][4];

    auto loadrow = [&](int r, int par) {
        float a0 = 0.f, b0 = 0.f, a1 = 0.f, b1 = 0.f;
        if (r >= 0 && r < H_) {          // wave-uniform scalar branch
            const int ro = r * W_;
            if (vm) { a0 = p1[ro + gxm]; b0 = p2[ro + gxm]; }
            if (vh) { a1 = p1[ro + gxh]; b1 = p2[ro + gxh]; }
        }
        pre[par][0] = a0; pre[par][1] = b0; pre[par][2] = a1; pre[par][3] = b1;
    };
    auto store = [&](int par) {
        rowbuf[w][par][lane] = make_float2(pre[par][0], pre[par][1]);
        if (lane < 10) rowbuf[w][par][64 + lane] = make_float2(pre[par][2], pre[par][3]);
    };

    // 11 pending output rows x 5 conv fields, statically indexed registers.
    float acc[11][5];
    #pragma unroll
    for (int s = 0; s < 11; ++s)
        #pragma unroll
        for (int f = 0; f < 5; ++f) acc[s][f] = 0.f;

    float psum = 0.f;

    // Prologue: rows 0 and 1; row 0 staged to LDS parity 0, row 1 held in regs.
    loadrow(y0 - 5, 0);
    loadrow(y0 - 4, 1);
    store(0);
    FENCE();

    #pragma unroll
    for (int i = 0; i < NIN; ++i) {
        const int sl  = i % 11;          // compile-time under full unroll
        const int cur = i & 1;

        // Prefetch row i+2 (distance 2: consumed by the ds_write at the END
        // of iteration i+1 -> >= 2 fenced iterations of latency cover).
        // Row parity (i+2)&1 == cur; pre[cur] held row i, already in LDS.
        if (i + 2 < NIN) loadrow(y0 - 5 + i + 2, cur);

        // Horizontal 11-tap pass over 5 fields from LDS buffer `cur`.
        float s1 = 0.f, s2 = 0.f, s11 = 0.f, s22 = 0.f, s12 = 0.f;
        #pragma unroll
        for (int t = 0; t < 11; ++t) {
            const float2 v = rowbuf[w][cur][lane + t];
            const float ga = G[t] * v.x;
            const float gb = G[t] * v.y;
            s1 += ga;
            s2 += gb;
            s11 = fmaf(ga, v.x, s11);
            s22 = fmaf(gb, v.y, s22);
            s12 = fmaf(ga, v.y, s12);
        }

        // Vertical accumulation into the 11 pending outputs (static slots).
        #pragma unroll
        for (int m = 0; m < 11; ++m) {
            const int s = (sl + m) % 11;
            const float gw = G[10 - m];
            acc[s][0] = fmaf(gw, s1,  acc[s][0]);
            acc[s][1] = fmaf(gw, s2,  acc[s][1]);
            acc[s][2] = fmaf(gw, s11, acc[s][2]);
            acc[s][3] = fmaf(gw, s22, acc[s][3]);
            acc[s][4] = fmaf(gw, s12, acc[s][4]);
        }

        // Output row o = y0 + i - 10 completes in slot sl at i >= 10.
        if (i >= 10) {
            const float mu1 = acc[sl][0], mu2 = acc[sl][1];
            const float x11 = acc[sl][2], x22 = acc[sl][3], x12 = acc[sl][4];
            const float mu1s = mu1 * mu1, mu2s = mu2 * mu2, mu12 = mu1 * mu2;
            const float num = (2.f * mu12 + 1e-4f) * (2.f * (x12 - mu12) + 9e-4f) + 1e-5f;
            const float den = (mu1s + mu2s + 1e-4f)
                            * ((x11 - mu1s) + (x22 - mu2s) + 9e-4f) + 1e-5f;
            psum += __fdividef(num, den);
        }
        // Slot sl recycled: always reset.
        #pragma unroll
        for (int f = 0; f < 5; ++f) acc[sl][f] = 0.f;

        // Stage row i+1 (loaded one full iteration ago) into the other buffer.
        if (i + 1 < NIN) store((i + 1) & 1);
        // Fence: DS ops may not cross iterations (hw DS pipe in-order per wave).
        FENCE();
    }

    // Wave reduce -> block reduce -> one atomic per block (1536 total).
    #pragma unroll
    for (int off = 32; off > 0; off >>= 1) psum += __shfl_xor(psum, off, 64);
    if (lane == 0) blksum[w] = psum;
    __syncthreads();
    if (tid == 0) {
        atomicAdd(accum, blksum[0] + blksum[1] + blksum[2] + blksum[3]);
    }
}

__global__ void ssim_final(const float* __restrict__ accum, float* __restrict__ out) {
    out[0] = 1.0f - accum[0] * (1.0f / 6291456.0f);  // B*C*H*MW = 16*3*512*256
}

extern "C" void kernel_launch(void* const* d_in, const int* in_sizes, int n_in,
                              void* d_out, int out_size, void* d_ws, size_t ws_size,
                              hipStream_t stream) {
    const float* img1 = (const float*)d_in[0];
    const float* img2 = (const float*)d_in[1];
    const int*   pos  = (const int*)d_in[2];
    float* out = (float*)d_out;
    float* acc = (float*)d_ws;

    hipMemsetAsync(acc, 0, sizeof(float), stream);

    // 48 (b,ch) images x 32 row strips; each block = 4 waves = 4 column strips.
    ssim_main<<<B_ * C_ * NRS, 256, 0, stream>>>(img1, img2, pos, acc);
    ssim_final<<<1, 1, 0, stream>>>(acc, out);
}

// Round 5
// 56.032 us; speedup vs baseline: 3.1934x; 3.1934x over previous
//
#include <hip/hip_runtime.h>

// Problem constants (fixed by setup_inputs).
#define B_     16
#define C_     3
#define H_     512
#define W_     1024
#define MW     256         // mask_width
#define RS     12          // output rows per strip
#define NSTRIP 43          // 43*12 = 516 >= 512 (last strip ragged)
#define NIN    (RS + 10)   // 22 input rows streamed per strip

#define FENCE() do { __builtin_amdgcn_sched_barrier(0); \
                     __builtin_amdgcn_wave_barrier();   \
                     __builtin_amdgcn_sched_barrier(0); } while (0)

__global__ __launch_bounds__(256) void ssim_main(const float* __restrict__ img1,
                                                 const float* __restrict__ img2,
                                                 const int*   __restrict__ mask_pos,
                                                 float*       __restrict__ accum) {
    // Gaussian weights = float64 exp/normalize, precomputed to float literals.
    constexpr float G[11] = {
        0.00102838f, 0.00759876f, 0.03600077f, 0.10936070f, 0.21300553f,
        0.26601173f, 0.21300553f, 0.10936070f, 0.03600077f, 0.00759876f,
        0.00102838f };

    // Per-wave double-buffered 74-col {img1,img2} row ring. ~5 KB total.
    __shared__ float2 rowbuf[4][2][80];
    __shared__ float  blksum[4];

    const int tid  = threadIdx.x;
    const int w    = tid >> 6;
    const int lane = tid & 63;

    const int blk   = blockIdx.x;
    const int bc    = blk / NSTRIP;      // (b,ch) 0..47
    const int strip = blk - bc * NSTRIP; // row strip 0..42
    const int b     = bc / 3;

    int s0 = mask_pos[b];
    s0 = min(max(s0, 0), W_ - MW);

    const float* __restrict__ p1 = img1 + (size_t)bc * (H_ * W_);
    const float* __restrict__ p2 = img2 + (size_t)bc * (H_ * W_);

    const int y0  = strip * RS;
    const int sx0 = w << 6;              // column strip base within crop
    const int cxm = sx0 - 5 + lane;      // main staged column (crop coords)
    const int cxh = sx0 + 59 + lane;     // halo staged column (lane < 10)
    const bool vm = (cxm >= 0) && (cxm < MW);
    const bool vh = (lane < 10) && (cxh < MW);
    const int gxm = s0 + cxm;
    const int gxh = s0 + cxh;

    // Single in-flight prefetch register set (distance 1, round-3 proven).
    float pa0, pb0, pa1, pb1;
    auto loadrow = [&](int r) {
        pa0 = pb0 = pa1 = pb1 = 0.f;
        if (r >= 0 && r < H_) {          // wave-uniform branch
            const int ro = r * W_;
            if (vm) { pa0 = p1[ro + gxm]; pb0 = p2[ro + gxm]; }
            if (vh) { pa1 = p1[ro + gxh]; pb1 = p2[ro + gxh]; }
        }
    };

    // 11 pending output rows x 5 conv fields; indices static under unroll-11.
    float acc[11][5];
    #pragma unroll
    for (int s = 0; s < 11; ++s)
        #pragma unroll
        for (int f = 0; f < 5; ++f) acc[s][f] = 0.f;

    float psum = 0.f;
    int cur = 0;                         // runtime LDS parity (fine: LDS, not VGPR array)

    // Prologue: stage streamed row 0 (input row y0-5) into parity 0.
    loadrow(y0 - 5);
    rowbuf[w][0][lane] = make_float2(pa0, pb0);
    if (lane < 10) rowbuf[w][0][64 + lane] = make_float2(pa1, pb1);
    FENCE();

    for (int ii = 0; ii < NIN; ii += 11) {
        #pragma unroll
        for (int j = 0; j < 11; ++j) {
            const int i = ii + j;        // streamed row index 0..21
            const bool notlast = (i + 1 < NIN);

            // Prefetch row i+1 into registers (hidden under this row's math).
            if (notlast) loadrow(y0 - 4 + i);

            // Horizontal 11-tap pass over 5 fields from LDS buffer `cur`.
            float s1 = 0.f, s2 = 0.f, s11 = 0.f, s22 = 0.f, s12 = 0.f;
            #pragma unroll
            for (int t = 0; t < 11; ++t) {
                const float2 v = rowbuf[w][cur][lane + t];
                const float ga = G[t] * v.x;
                const float gb = G[t] * v.y;
                s1 += ga;
                s2 += gb;
                s11 = fmaf(ga, v.x, s11);
                s22 = fmaf(gb, v.y, s22);
                s12 = fmaf(ga, v.y, s12);
            }

            // Vertical accumulation into the 11 pending outputs (static slots).
            #pragma unroll
            for (int m = 0; m < 11; ++m) {
                const int s = (j + m) % 11;
                const float gw = G[10 - m];
                acc[s][0] = fmaf(gw, s1,  acc[s][0]);
                acc[s][1] = fmaf(gw, s2,  acc[s][1]);
                acc[s][2] = fmaf(gw, s11, acc[s][2]);
                acc[s][3] = fmaf(gw, s22, acc[s][3]);
                acc[s][4] = fmaf(gw, s12, acc[s][4]);
            }

            // Output row o = y0 + i - 10 completes in slot j at i >= 10.
            if (i >= 10) {
                const int o = y0 + i - 10;
                if (o < H_) {            // ragged last strip guard
                    const float mu1 = acc[j][0], mu2 = acc[j][1];
                    const float x11 = acc[j][2], x22 = acc[j][3], x12 = acc[j][4];
                    const float mu1s = mu1 * mu1, mu2s = mu2 * mu2, mu12 = mu1 * mu2;
                    const float num = (2.f * mu12 + 1e-4f) * (2.f * (x12 - mu12) + 9e-4f) + 1e-5f;
                    const float den = (mu1s + mu2s + 1e-4f)
                                    * ((x11 - mu1s) + (x22 - mu2s) + 9e-4f) + 1e-5f;
                    psum += __fdividef(num, den);
                }
            }
            // Slot j recycled: always reset.
            #pragma unroll
            for (int f = 0; f < 5; ++f) acc[j][f] = 0.f;

            // Stage prefetched row i+1 into the other buffer.
            if (notlast) {
                rowbuf[w][cur ^ 1][lane] = make_float2(pa0, pb0);
                if (lane < 10) rowbuf[w][cur ^ 1][64 + lane] = make_float2(pa1, pb1);
            }
            cur ^= 1;
            // Fence: no DS op crosses iterations (hw DS pipe in-order per wave).
            FENCE();
        }
    }

    // Wave reduce -> block reduce -> one atomic per block (2064 total).
    #pragma unroll
    for (int off = 32; off > 0; off >>= 1) psum += __shfl_xor(psum, off, 64);
    if (lane == 0) blksum[w] = psum;
    __syncthreads();
    if (tid == 0) {
        atomicAdd(accum, blksum[0] + blksum[1] + blksum[2] + blksum[3]);
    }
}

__global__ void ssim_final(const float* __restrict__ accum, float* __restrict__ out) {
    out[0] = 1.0f - accum[0] * (1.0f / 6291456.0f);  // B*C*H*MW = 16*3*512*256
}

extern "C" void kernel_launch(void* const* d_in, const int* in_sizes, int n_in,
                              void* d_out, int out_size, void* d_ws, size_t ws_size,
                              hipStream_t stream) {
    const float* img1 = (const float*)d_in[0];
    const float* img2 = (const float*)d_in[1];
    const int*   pos  = (const int*)d_in[2];
    float* out = (float*)d_out;
    float* acc = (float*)d_ws;

    hipMemsetAsync(acc, 0, sizeof(float), stream);

    // 48 (b,ch) images x 43 row strips; each block = 4 waves = 4 column strips.
    ssim_main<<<B_ * C_ * NSTRIP, 256, 0, stream>>>(img1, img2, pos, acc);
    ssim_final<<<1, 1, 0, stream>>>(acc, out);
}